// Round 1
// baseline (296.403 us; speedup 1.0000x reference)
//
#include <hip/hip_runtime.h>
#include <hip/hip_bf16.h>

#define EMB 16
#define HID 64
#define NE  8
#define TPG 64   // tokens per wave-group (one router lane per token)

typedef float f32x4 __attribute__((ext_vector_type(4)));
typedef short s16x4 __attribute__((ext_vector_type(4)));

// fp32 -> bf16, round-to-nearest-even (no NaN in this workload)
__device__ __forceinline__ short f2bf(float f) {
    union { float f; unsigned u; } v; v.f = f;
    unsigned u = v.u;
    u += 0x7FFFu + ((u >> 16) & 1u);
    return (short)(u >> 16);
}

__global__ __launch_bounds__(256, 2)
void moe_fused(const float* __restrict__ x, const float* __restrict__ Wr,
               const float* __restrict__ br, const float* __restrict__ W1,
               const float* __restrict__ b1, const float* __restrict__ W2,
               const float* __restrict__ b2, float* __restrict__ out,
               int n_tokens)
{
    __shared__ __align__(16) float wr_lds[EMB * NE];
    __shared__ __align__(16) float br_lds[NE];
    __shared__ __align__(16) float b1_lds[NE * HID];

    const int tid = threadIdx.x;
    for (int i = tid; i < EMB * NE; i += 256) wr_lds[i] = Wr[i];
    for (int i = tid; i < NE * HID; i += 256) b1_lds[i] = b1[i];
    if (tid < NE) br_lds[tid] = br[tid];
    __syncthreads();

    const int lane = tid & 63;
    const int col  = lane & 15;   // token-col (G2 D) / emb-col / hid-row (G1 A)
    const int cg   = lane >> 4;   // 0..3 k-group

    // ---- weight fragments, register-resident (loaded once per wave, L2-hot) ----
    // G1 (swapped): A = W1^T tile n: A[row=hid_loc=col][k=4cg+j] = W1[e][4cg+j][16n+col]
    // G2:           B = W2 ktile q:  B[k=4cg+j][col=emb=col]     = W2[e][16q+4cg+j][col]
    s16x4 w1f[NE][4], w2f[NE][4];
    float b2f[NE];
#pragma unroll
    for (int e = 0; e < NE; ++e) {
#pragma unroll
        for (int n = 0; n < 4; ++n) {
            s16x4 t;
#pragma unroll
            for (int j = 0; j < 4; ++j)
                t[j] = f2bf(W1[(e * EMB + 4 * cg + j) * HID + 16 * n + col]);
            w1f[e][n] = t;
        }
#pragma unroll
        for (int q = 0; q < 4; ++q) {
            s16x4 t;
#pragma unroll
            for (int j = 0; j < 4; ++j)
                t[j] = f2bf(W2[(e * HID + 16 * q + 4 * cg + j) * EMB + col]);
            w2f[e][q] = t;
        }
        b2f[e] = b2[e * EMB + col];
    }

    const int n_groups = n_tokens / TPG;
    const int gw = blockIdx.x * 4 + (tid >> 6);
    const int nw = gridDim.x * 4;

    for (int g = gw; g < n_groups; g += nw) {
        const int tok0 = g * TPG;

        // ---------------- router: lane owns token tok0+lane (fp32, fp64 rescue) ----------------
        float xk[EMB];
        {
            const f32x4* xp = (const f32x4*)(x + (tok0 + lane) * EMB);
#pragma unroll
            for (int q4 = 0; q4 < 4; ++q4) {
                f32x4 v = xp[q4];
#pragma unroll
                for (int j = 0; j < 4; ++j) xk[q4 * 4 + j] = v[j];
            }
        }
        float lg[NE];
#pragma unroll
        for (int e = 0; e < NE; ++e) lg[e] = br_lds[e];
#pragma unroll
        for (int k = 0; k < EMB; ++k) {
            const float xv = xk[k];
#pragma unroll
            for (int e = 0; e < NE; ++e) lg[e] = fmaf(xv, wr_lds[k * NE + e], lg[e]);
        }
        // top-3 scan (m3 only gates the fp64 rescue)
        float m1 = -1e30f, m2 = -1e30f, m3 = -1e30f;
#pragma unroll
        for (int e = 0; e < NE; ++e) {
            const float v  = lg[e];
            const float hi = fmaxf(m1, v), lo = fminf(m1, v);
            const float hi2 = fmaxf(m2, lo), lo2 = fminf(m2, lo);
            m1 = hi; m2 = hi2; m3 = fmaxf(m3, lo2);
        }
        bool sel[NE];
        if (m2 - m3 < 1e-4f) {
            // near-tie at the top-2 boundary: recompute logits exactly (rare path)
            double dl[NE];
#pragma unroll
            for (int e = 0; e < NE; ++e) dl[e] = (double)br_lds[e];
#pragma unroll
            for (int k = 0; k < EMB; ++k) {
                const double xv = (double)xk[k];
#pragma unroll
                for (int e = 0; e < NE; ++e)
                    dl[e] = fma(xv, (double)wr_lds[k * NE + e], dl[e]);
            }
            double M1 = -1e300, M2 = -1e300;
#pragma unroll
            for (int e = 0; e < NE; ++e) {
                const double v = dl[e];
                const double hi = fmax(M1, v);
                M2 = fmax(M2, fmin(M1, v));
                M1 = hi;
            }
#pragma unroll
            for (int e = 0; e < NE; ++e) sel[e] = (dl[e] >= M2);
        } else {
#pragma unroll
            for (int e = 0; e < NE; ++e) sel[e] = (lg[e] >= m2);
        }
        float w[NE], s = 0.f;
#pragma unroll
        for (int e = 0; e < NE; ++e) { w[e] = __expf(lg[e] - m1); s += w[e]; }
        const float inv = 1.0f / s;
#pragma unroll
        for (int e = 0; e < NE; ++e) w[e] = sel[e] ? w[e] * inv : 0.0f;

        // ---------------- 4 MFMA tiles of 16 tokens ----------------
        for (int T = 0; T < 4; ++T) {
            // G1 B-frag: B[k=4cg+j][tok=col] = x[tok0+16T+col][4cg+j]
            f32x4 xv = *(const f32x4*)(x + (tok0 + 16 * T + col) * EMB + 4 * cg);
            s16x4 xb;
#pragma unroll
            for (int j = 0; j < 4; ++j) xb[j] = f2bf(xv[j]);

            f32x4 oacc = {0.f, 0.f, 0.f, 0.f};
#pragma unroll
            for (int e = 0; e < NE; ++e) {
                // G1: h^T tile n, C-in = b1  (lane: h[tok=col][hid=16n+4cg+r])
                f32x4 h[4];
#pragma unroll
                for (int n = 0; n < 4; ++n) {
                    f32x4 cin = *(const f32x4*)(b1_lds + e * HID + 16 * n + 4 * cg);
                    h[n] = __builtin_amdgcn_mfma_f32_16x16x16bf16_1k(w1f[e][n], xb, cin, 0, 0, 0);
                }
                // G2: eo[tok][emb], K=64 as 4 chained k-tiles; A-frag == relu(h[q]) verbatim
                f32x4 eo = {b2f[e], b2f[e], b2f[e], b2f[e]};
#pragma unroll
                for (int q = 0; q < 4; ++q) {
                    s16x4 a;
#pragma unroll
                    for (int j = 0; j < 4; ++j) a[j] = f2bf(fmaxf(h[q][j], 0.f));
                    eo = __builtin_amdgcn_mfma_f32_16x16x16bf16_1k(a, w2f[e][q], eo, 0, 0, 0);
                }
                // weighted accumulate: lane reg r holds token 4cg+r (local), owner lane 16T+4cg+r
#pragma unroll
                for (int r = 0; r < 4; ++r) {
                    const float wv = __shfl(w[e], 16 * T + 4 * cg + r, 64);
                    oacc[r] = fmaf(wv, eo[r], oacc[r]);
                }
            }
#pragma unroll
            for (int r = 0; r < 4; ++r)
                out[(tok0 + 16 * T + 4 * cg + r) * EMB + col] = oacc[r];
        }
    }
}

extern "C" void kernel_launch(void* const* d_in, const int* in_sizes, int n_in,
                              void* d_out, int out_size, void* d_ws, size_t ws_size,
                              hipStream_t stream) {
    const float* x  = (const float*)d_in[0];
    const float* Wr = (const float*)d_in[1];
    const float* br = (const float*)d_in[2];
    const float* W1 = (const float*)d_in[3];
    const float* b1 = (const float*)d_in[4];
    const float* W2 = (const float*)d_in[5];
    const float* b2 = (const float*)d_in[6];
    float* out = (float*)d_out;

    const int n_tokens = in_sizes[0] / EMB;   // 64*4096 = 262144
    // 512 blocks * 4 waves = 2048 waves at ~2 waves/SIMD -> chip exactly filled,
    // each wave handles 2 groups of 64 tokens (amortizes register weight setup).
    hipLaunchKernelGGL(moe_fused, dim3(512), dim3(256), 0, stream,
                       x, Wr, br, W1, b1, W2, b2, out, n_tokens);
}

// Round 2
// 94.059 us; speedup vs baseline: 3.1512x; 3.1512x over previous
//
#include <hip/hip_runtime.h>
#include <hip/hip_bf16.h>

#define EMB 16
#define HID 64
#define NE  8
#define TPG 64   // tokens per wave-group (one router lane per token)

typedef float f32x4 __attribute__((ext_vector_type(4)));
typedef short s16x4 __attribute__((ext_vector_type(4)));

// fp32 -> bf16, round-to-nearest-even (no NaN in this workload)
__device__ __forceinline__ short f2bf(float f) {
    union { float f; unsigned u; } v; v.f = f;
    unsigned u = v.u;
    u += 0x7FFFu + ((u >> 16) & 1u);
    return (short)(u >> 16);
}

__global__ __launch_bounds__(256, 2)
void moe_fused(const float* __restrict__ x, const float* __restrict__ Wr,
               const float* __restrict__ br, const float* __restrict__ W1,
               const float* __restrict__ b1, const float* __restrict__ W2,
               const float* __restrict__ b2, float* __restrict__ out,
               int n_tokens)
{
    // Weight fragments live in LDS (NOT registers — round-1 spilled 700 MB of
    // scratch traffic keeping 128 VGPRs of weights per lane).
    __shared__ __align__(16) s16x4 w1lds[NE * 4 * 64];   // 16 KB: [e][n][lane]
    __shared__ __align__(16) s16x4 w2lds[NE * 4 * 64];   // 16 KB: [e][q][lane]
    __shared__ __align__(16) float b1_lds[NE * HID];     // 2 KB
    __shared__ __align__(16) float wr_lds[EMB * NE];
    __shared__ __align__(16) float br_lds[NE];
    __shared__ __align__(16) float b2_lds[NE * EMB];
    __shared__ __align__(16) float wt_lds[4 * NE * TPG]; // 8 KB, wave-private gate weights

    const int tid = threadIdx.x;

    // ---- one-time per block: convert weights fp32->bf16 into per-lane fragment order ----
    // w1lds[(e*4+n)*64 + lane(cg,col)][j] = W1[e][4cg+j][16n+col]   (G1 A-frag, swapped)
    // w2lds[(e*4+q)*64 + lane(cg,col)][j] = W2[e][16q+4cg+j][col]   (G2 B-frag)
    for (int s = tid; s < NE * 4 * 64; s += 256) {
        const int e = s >> 8, nq = (s >> 6) & 3, l = s & 63;
        const int cc = l & 15, gg = (l >> 4) & 3;
        s16x4 t1, t2;
#pragma unroll
        for (int j = 0; j < 4; ++j) {
            t1[j] = f2bf(W1[(e * EMB + 4 * gg + j) * HID + 16 * nq + cc]);
            t2[j] = f2bf(W2[(e * HID + 16 * nq + 4 * gg + j) * EMB + cc]);
        }
        w1lds[s] = t1;
        w2lds[s] = t2;
    }
    for (int i = tid; i < NE * HID; i += 256) b1_lds[i] = b1[i];
    if (tid < EMB * NE) wr_lds[tid] = Wr[tid];
    if (tid < NE * EMB) b2_lds[tid] = b2[tid];
    if (tid < NE) br_lds[tid] = br[tid];
    __syncthreads();

    const int lane = tid & 63;
    const int wid  = tid >> 6;
    const int col  = lane & 15;   // token-col (G2 D) / emb-col / hid-row (G1 A)
    const int cg   = lane >> 4;   // 0..3 k-group
    float* wt = wt_lds + wid * (NE * TPG);

    const int n_groups = n_tokens / TPG;
    const int gw = blockIdx.x * 4 + wid;
    const int nw = gridDim.x * 4;

    for (int g = gw; g < n_groups; g += nw) {
        const int tok0 = g * TPG;

        // ---------------- router: lane owns token tok0+lane (fp32, fp64 rescue) ----------------
        {
            float xk[EMB];
            const f32x4* xp = (const f32x4*)(x + (tok0 + lane) * EMB);
#pragma unroll
            for (int q4 = 0; q4 < 4; ++q4) {
                f32x4 v = xp[q4];
#pragma unroll
                for (int j = 0; j < 4; ++j) xk[q4 * 4 + j] = v[j];
            }
            float lg[NE];
#pragma unroll
            for (int e = 0; e < NE; ++e) lg[e] = br_lds[e];
#pragma unroll
            for (int k = 0; k < EMB; ++k) {
                const float xv = xk[k];
#pragma unroll
                for (int e = 0; e < NE; ++e) lg[e] = fmaf(xv, wr_lds[k * NE + e], lg[e]);
            }
            // top-3 scan (m3 only gates the fp64 rescue)
            float m1 = -1e30f, m2 = -1e30f, m3 = -1e30f;
#pragma unroll
            for (int e = 0; e < NE; ++e) {
                const float v   = lg[e];
                const float hi  = fmaxf(m1, v), lo  = fminf(m1, v);
                const float hi2 = fmaxf(m2, lo), lo2 = fminf(m2, lo);
                m1 = hi; m2 = hi2; m3 = fmaxf(m3, lo2);
            }
            bool sel[NE];
            if (m2 - m3 < 1e-4f) {
                // near-tie at the top-2 boundary: recompute logits exactly (rare path)
                double dl[NE];
#pragma unroll
                for (int e = 0; e < NE; ++e) dl[e] = (double)br_lds[e];
#pragma unroll
                for (int k = 0; k < EMB; ++k) {
                    const double xv = (double)xk[k];
#pragma unroll
                    for (int e = 0; e < NE; ++e)
                        dl[e] = fma(xv, (double)wr_lds[k * NE + e], dl[e]);
                }
                double M1 = -1e300, M2 = -1e300;
#pragma unroll
                for (int e = 0; e < NE; ++e) {
                    const double v  = dl[e];
                    const double hi = fmax(M1, v);
                    M2 = fmax(M2, fmin(M1, v));
                    M1 = hi;
                }
#pragma unroll
                for (int e = 0; e < NE; ++e) sel[e] = (dl[e] >= M2);
            } else {
#pragma unroll
                for (int e = 0; e < NE; ++e) sel[e] = (lg[e] >= m2);
            }
            float w[NE], s = 0.f;
#pragma unroll
            for (int e = 0; e < NE; ++e) { w[e] = __expf(lg[e] - m1); s += w[e]; }
            const float inv = 1.0f / s;
            // park per-token gate weights in wave-private LDS (avoids runtime-indexed
            // register array -> scratch once the e-loop is not unrolled)
#pragma unroll
            for (int e = 0; e < NE; ++e)
                wt[e * TPG + lane] = sel[e] ? w[e] * inv : 0.0f;
        }

        // ---------------- B-fragments of x for the 4 token tiles ----------------
        s16x4 xb[4];
#pragma unroll
        for (int T = 0; T < 4; ++T) {
            f32x4 xv = *(const f32x4*)(x + (tok0 + 16 * T + col) * EMB + 4 * cg);
#pragma unroll
            for (int j = 0; j < 4; ++j) xb[T][j] = f2bf(xv[j]);
        }

        f32x4 oacc[4];
#pragma unroll
        for (int T = 0; T < 4; ++T) oacc[T] = (f32x4){0.f, 0.f, 0.f, 0.f};

        // ---------------- expert loop: fragments streamed from LDS, low reg pressure ----------------
#pragma unroll 1
        for (int e = 0; e < NE; ++e) {
            s16x4 a1[4], a2[4];
            f32x4 b1c[4];
#pragma unroll
            for (int n = 0; n < 4; ++n) {
                a1[n]  = w1lds[(e * 4 + n) * 64 + lane];
                a2[n]  = w2lds[(e * 4 + n) * 64 + lane];
                b1c[n] = *(const f32x4*)(b1_lds + e * HID + 16 * n + 4 * cg);
            }
            const float b2v = b2_lds[e * EMB + col];
            const float* wte = wt + e * TPG;

#pragma unroll
            for (int T = 0; T < 4; ++T) {
                // G1: h^T tile n, C-in = b1  (lane: h[tok=col][hid=16n+4cg+r])
                f32x4 h[4];
#pragma unroll
                for (int n = 0; n < 4; ++n)
                    h[n] = __builtin_amdgcn_mfma_f32_16x16x16bf16_1k(a1[n], xb[T], b1c[n], 0, 0, 0);
                // G2: eo[tok][emb], K=64 as 4 chained k-tiles; A-frag == relu(h[q]) verbatim
                f32x4 eo = {b2v, b2v, b2v, b2v};
#pragma unroll
                for (int q = 0; q < 4; ++q) {
                    s16x4 a;
#pragma unroll
                    for (int j = 0; j < 4; ++j) a[j] = f2bf(fmaxf(h[q][j], 0.f));
                    eo = __builtin_amdgcn_mfma_f32_16x16x16bf16_1k(a, a2[q], eo, 0, 0, 0);
                }
                // weighted accumulate: lane reg r holds token 16T+4cg+r (broadcast LDS read)
#pragma unroll
                for (int r = 0; r < 4; ++r)
                    oacc[T][r] = fmaf(wte[16 * T + 4 * cg + r], eo[r], oacc[T][r]);
            }
        }

#pragma unroll
        for (int T = 0; T < 4; ++T)
#pragma unroll
            for (int r = 0; r < 4; ++r)
                out[(tok0 + 16 * T + 4 * cg + r) * EMB + col] = oacc[T][r];
    }
}

extern "C" void kernel_launch(void* const* d_in, const int* in_sizes, int n_in,
                              void* d_out, int out_size, void* d_ws, size_t ws_size,
                              hipStream_t stream) {
    const float* x  = (const float*)d_in[0];
    const float* Wr = (const float*)d_in[1];
    const float* br = (const float*)d_in[2];
    const float* W1 = (const float*)d_in[3];
    const float* b1 = (const float*)d_in[4];
    const float* W2 = (const float*)d_in[5];
    const float* b2 = (const float*)d_in[6];
    float* out = (float*)d_out;

    const int n_tokens = in_sizes[0] / EMB;   // 64*4096 = 262144
    // 512 blocks * 4 waves = 2048 waves, 2 blocks/CU -> each wave handles exactly
    // 2 groups of 64 tokens (amortizes the per-block weight conversion).
    hipLaunchKernelGGL(moe_fused, dim3(512), dim3(256), 0, stream,
                       x, Wr, br, W1, b1, W2, b2, out, n_tokens);
}